// Round 8
// baseline (1468.543 us; speedup 1.0000x reference)
//
#include <hip/hip_runtime.h>
#include <cstdint>
#include <math.h>

// GREEN since r6. Ladder: r15 490 -> r17 326 (pk_fma full-rate) -> r19 285
// (DPP butterfly + 2-chain pk structure) -> r22 344 REGRESSION (4-chain,
// VGPR=136 proved RA spilled the 192-float U array to scratch at 1 wave/
// SIMD). LAW (r20/r21/r22): this RA caps ~136 VGPR here; 192 resident U
// floats will NEVER be granted (keep-alive ties, LDS laundering, memory
// clobbers all defeated). STOP fighting the allocator.
// THIS ROUND r23: revert to r19 structure; make the U stream CHEAP instead.
//  - one-time pack kernel writes U into d_ws in per-lane consumption order:
//    lane j's column = 192 floats contiguous at ws+j*768B, chunk c =
//    {Uz[4c..4c+3],Ur[4c..4c+3],Un[4c..4c+3]} = 3 x float4.
//  - step loop reads U as 48 global_load_dwordx4 with IMMEDIATE offsets
//    from one base reg -> ~350 addr-VALU/step deleted; pairs land
//    even-aligned for pk-FMA (zero marshalling). 48KB working set is
//    L1/L2-resident. Remat per step is now what we WANT.
//  - instr/step/wave ~870 -> ~430. Same values, same FMA order, same PRNG
//    -> absmax must stay 0.0.
// Predict: dur 283 -> 160-210us, VGPR 100-140, VALUBusy 55-65%, LDS 4096.
// Failure: dur flat ~280 + VALUBusy low => VMEM-bound -> next: split Un to
// LDS b128 (r15 pattern, +16KB) and keep z/r from ws (32 loads).
// EMPIRICAL RULES: only __launch_bounds__(64,1) gives the full reg budget;
// OccupancyPercent counter is gfx94x fallback (untrustworthy); occupancy is
// grid-capped at 2 waves/SIMD in the 64-thread structure.
// Locked-in: PRNG = partitionable threefry (key_t = tf((0,42),(0,t)); bits =
// o0^o1 of tf(key_t,(0,2s+cat))); f32 in/out; out = [4096*144][4096];
// decisions rounding-robust (6 arithmetic variants, bit-identical streams).

#define NSAMP 4096
#define NSTEP 144
#define HID 64
#define CPB 2            // chains per block (one wave)

typedef float v4f  __attribute__((ext_vector_type(4)));
typedef float v2f  __attribute__((ext_vector_type(2)));

// ---- JAX threefry2x32 (20 rounds, key-inject every 4) ----
__device__ __forceinline__ void threefry2x32(uint32_t k0, uint32_t k1,
                                             uint32_t x0, uint32_t x1,
                                             uint32_t& o0, uint32_t& o1) {
  const uint32_t ks0 = k0, ks1 = k1, ks2 = k0 ^ k1 ^ 0x1BD11BDAu;
  x0 += ks0; x1 += ks1;
#define TF_ROUND(d) { x0 += x1; x1 = (x1 << (d)) | (x1 >> (32 - (d))); x1 ^= x0; }
  TF_ROUND(13) TF_ROUND(15) TF_ROUND(26) TF_ROUND(6)
  x0 += ks1; x1 += ks2 + 1u;
  TF_ROUND(17) TF_ROUND(29) TF_ROUND(16) TF_ROUND(24)
  x0 += ks2; x1 += ks0 + 2u;
  TF_ROUND(13) TF_ROUND(15) TF_ROUND(26) TF_ROUND(6)
  x0 += ks0; x1 += ks1 + 3u;
  TF_ROUND(17) TF_ROUND(29) TF_ROUND(16) TF_ROUND(24)
  x0 += ks1; x1 += ks2 + 4u;
  TF_ROUND(13) TF_ROUND(15) TF_ROUND(26) TF_ROUND(6)
  x0 += ks2; x1 += ks0 + 5u;
#undef TF_ROUND
  o0 = x0; o1 = x1;
}

__device__ __forceinline__ float fsig(float x) {        // 1/(1+e^-x), stable
  return __builtin_amdgcn_rcpf(1.0f + __expf(-x));
}
__device__ __forceinline__ float ftanh(float x) {       // 1 - 2/(e^2x+1)
  const float e = __expf(2.0f * x);
  return 1.0f - 2.0f * __builtin_amdgcn_rcpf(e + 1.0f);
}

// Packed f32 FMA, chains (a,b) in (lo,hi). u-pair even-aligned; LO
// broadcasts its low element to both halves, HI the high one.
#define PKFMA_LO(acc, h2, up) \
  asm("v_pk_fma_f32 %0, %1, %2, %0 op_sel_hi:[1,0,1]" \
      : "+v"(acc) : "v"(h2), "v"(up));
#define PKFMA_HI(acc, h2, up) \
  asm("v_pk_fma_f32 %0, %1, %2, %0 op_sel:[0,1,0] op_sel_hi:[1,1,1]" \
      : "+v"(acc) : "v"(h2), "v"(up));

// DPP butterfly level: v += lane-swapped(v); bitwise == __shfl_xor(v,m)
// given the uniformity at each level (proven r19).
template <int CTRL>
__device__ __forceinline__ float dpp_add(float v) {
  union { float f; int i; } c; c.f = v;
  union { int i; float f; } r;
  r.i = __builtin_amdgcn_mov_dpp(c.i, CTRL, 0xF, 0xF, true);
  return v + r.f;
}
#define DPP_XOR1 0xB1
#define DPP_XOR2 0x4E
#define DPP_XOR4 0x141
#define DPP_XOR8 0x140

// ---- one-time U pack: ws[j*192 + c*12 + e], e:0-3 Uz[4c+e], 4-7 Ur, 8-11 Un
__global__ void pack_kernel(const float* __restrict__ U,
                            float* __restrict__ ws) {
  const int idx = blockIdx.x * 256 + threadIdx.x;
  if (idx < HID * 192) {
    const int j = idx / 192, rem = idx - j * 192;
    const int c = rem / 12, e = rem - c * 12;
    const int g = e >> 2, ee = e & 3;
    ws[idx] = U[(4 * c + ee) * 192 + g * 64 + j];
  }
}

__global__ __launch_bounds__(64, 1) void vmc_kernel(
    const float* __restrict__ W, const float* __restrict__ Upk,
    const float* __restrict__ B, const float* __restrict__ Wd,
    const float* __restrict__ Bd, float* __restrict__ out) {
  const int j = threadIdx.x;           // hidden unit owned by this lane
  const int s_base = blockIdx.x * CPB; // first of 2 chains in this block

  __shared__ __align__(16) float2 hsh2[HID];      // h[unit] = {chain a, chain b}
  __shared__ uint2 kkeys[NSTEP];
  __shared__ float gsh[CPB * 2 * NSTEP];          // gumbels [c*288 + 2t + cat]

  // --- per-step keys: key_t = threefry((0,42),(0,t)) ---
#pragma unroll 1
  for (int t = j; t < NSTEP; t += HID) {
    uint32_t o0, o1;
    threefry2x32(0u, 42u, 0u, (uint32_t)t, o0, o1);
    kkeys[t].x = o0; kkeys[t].y = o1;
  }
  hsh2[j] = float2{0.0f, 0.0f};
  __syncthreads();

  // --- gumbels: EXACT path kept (f64 libm, one-time): bits = o0^o1 of
  // tf(key_t,(0,2s+cat)); u = bitcast(bits>>9|0x3f800000)-1 clamped tiny ---
#pragma unroll 1
  for (int id = j; id < CPB * 2 * NSTEP; id += HID) {
    const int c = id / 288;
    const int idx = id - c * 288;
    const uint2 kt = kkeys[idx >> 1];
    const uint32_t i = 2u * (uint32_t)(s_base + c) + (uint32_t)(idx & 1);
    uint32_t o0, o1;
    threefry2x32(kt.x, kt.y, 0u, i, o0, o1);
    const uint32_t bits = o0 ^ o1;
    union { uint32_t u; float f; } cv; cv.u = (bits >> 9) | 0x3F800000u;
    float uf = cv.f - 1.0f;
    uf = fmaxf(uf, 1.17549435e-38f);
    const float inner = (float)log((double)uf);
    gsh[id] = -(float)log((double)(-inner));
  }
  __syncthreads();

  // --- lane j's packed U column base: 192 floats, consumption-ordered,
  // 16B-aligned (768B stride). Loads below use immediate offsets only. ---
  const float* Up = Upk + j * 192;

  const float b1z = B[192 + j], b1r = B[256 + j], b1n = B[320 + j];
  const float b0z = B[j],       b0r = B[64 + j],  b0n = B[128 + j];
  const float xW0z = W[j]       + b0z, xW1z = W[192 + j] + b0z;
  const float xW0r = W[64 + j]  + b0r, xW1r = W[256 + j] + b0r;
  const float xW0n = W[128 + j] + b0n, xW1n = W[320 + j] + b0n;
  const float wdd = Wd[2*j + 1] - Wd[2*j];   // dense difference column
  const float bdd = Bd[1] - Bd[0];

  float ha = 0.0f, hb_ = 0.0f;
  float logPa = 0.0f, logPb = 0.0f;
  float axz = b0z, axr = b0r, axn = b0n;  // t=0: x=0 -> xm = b[0]
  float bxz = b0z, bxr = b0r, bxn = b0n;
  // loop-carried packed dot accumulators {chain a, chain b}; h_{-1}=0 -> 0
  v2f hz2 = {0.f, 0.f}, hr2 = {0.f, 0.f}, hn2 = {0.f, 0.f};

  for (int t = 0; t < NSTEP; ++t) {
    // ---- gates from the PREVIOUS iteration's dot (software pipeline) ----
    {
      const float az = axz + (hz2.x + b1z), ar = axr + (hr2.x + b1r);
      const float zz = fsig(az), rr = fsig(ar);
      const float hh = ftanh(axn + rr * (hn2.x + b1n));
      ha = zz * ha + (1.0f - zz) * hh;
    }
    {
      const float az = bxz + (hz2.y + b1z), ar = bxr + (hr2.y + b1r);
      const float zz = fsig(az), rr = fsig(ar);
      const float hh = ftanh(bxn + rr * (hn2.y + b1n));
      hb_ = zz * hb_ + (1.0f - zz) * hh;
    }
    hsh2[j] = float2{ha, hb_};   // single wave: LDS ops in program order

    // ---- dense: difference-reduction, butterfly m=1..32. Levels 1-8 via
    // DPP VALU (bit-exact), 16/32 via shfl. ----
    float da = ha * wdd, db = hb_ * wdd;
    da = dpp_add<DPP_XOR1>(da); db = dpp_add<DPP_XOR1>(db);
    da = dpp_add<DPP_XOR2>(da); db = dpp_add<DPP_XOR2>(db);
    da = dpp_add<DPP_XOR4>(da); db = dpp_add<DPP_XOR4>(db);
    da = dpp_add<DPP_XOR8>(da); db = dpp_add<DPP_XOR8>(db);
    da += __shfl_xor(da, 16, 64); db += __shfl_xor(db, 16, 64);
    da += __shfl_xor(da, 32, 64); db += __shfl_xor(db, 32, 64);

    int sma, smb;
    {
      const float d = da + bdd;
      const float p1 = fsig(d), p0 = fsig(-d);
      const float lp0 = __logf(1e-10f + p0);
      const float lp1 = __logf(1e-10f + p1);
      const float g0 = gsh[2*t], g1 = gsh[2*t + 1];
      sma = (lp1 + g1) > (lp0 + g0);
      logPa += sma ? lp1 : lp0;
      axz = sma ? xW1z : xW0z;
      axr = sma ? xW1r : xW0r;
      axn = sma ? xW1n : xW0n;
    }
    {
      const float d = db + bdd;
      const float p1 = fsig(d), p0 = fsig(-d);
      const float lp0 = __logf(1e-10f + p0);
      const float lp1 = __logf(1e-10f + p1);
      const float g0 = gsh[288 + 2*t], g1 = gsh[288 + 2*t + 1];
      smb = (lp1 + g1) > (lp0 + g0);
      logPb += smb ? lp1 : lp0;
      bxz = smb ? xW1z : xW0z;
      bxr = smb ? xW1r : xW0r;
      bxn = smb ? xW1n : xW0n;
    }
    if (j == 0) {
      out[(s_base + 0) * NSTEP + t] = sma ? 1.0f : 0.0f;
      out[(s_base + 1) * NSTEP + t] = smb ? 1.0f : 0.0f;
    }

    // ---- dot for NEXT step: hm = h_t @ U, k-ascending per half, packed
    // {a,b}. h pairs from LDS float2 broadcast; U streamed from the packed
    // ws column (3 dwordx4/chunk, immediate offsets, zero addr math).
    // Same values, same per-half order as r19 -> bit-identical decisions. ----
    hz2 = v2f{0.f, 0.f}; hr2 = v2f{0.f, 0.f}; hn2 = v2f{0.f, 0.f};
#define SV2(x, a, b) __builtin_shufflevector(x, x, a, b)
#define DOTC(c_) \
    { const v4f hA = *(const v4f*)&hsh2[(c_)*4]; \
      const v4f hB = *(const v4f*)&hsh2[(c_)*4 + 2]; \
      const v4f q0 = *(const v4f*)(Up + (c_)*12); \
      const v4f q1 = *(const v4f*)(Up + (c_)*12 + 4); \
      const v4f q2 = *(const v4f*)(Up + (c_)*12 + 8); \
      const v2f h0  = SV2(hA, 0, 1); \
      const v2f h1  = SV2(hA, 2, 3); \
      const v2f h2_ = SV2(hB, 0, 1); \
      const v2f h3  = SV2(hB, 2, 3); \
      const v2f uz01 = SV2(q0, 0, 1), uz23 = SV2(q0, 2, 3); \
      const v2f ur01 = SV2(q1, 0, 1), ur23 = SV2(q1, 2, 3); \
      const v2f un01 = SV2(q2, 0, 1), un23 = SV2(q2, 2, 3); \
      PKFMA_LO(hz2, h0,  uz01) PKFMA_LO(hr2, h0,  ur01) PKFMA_LO(hn2, h0,  un01) \
      PKFMA_HI(hz2, h1,  uz01) PKFMA_HI(hr2, h1,  ur01) PKFMA_HI(hn2, h1,  un01) \
      PKFMA_LO(hz2, h2_, uz23) PKFMA_LO(hr2, h2_, ur23) PKFMA_LO(hn2, h2_, un23) \
      PKFMA_HI(hz2, h3,  uz23) PKFMA_HI(hr2, h3,  ur23) PKFMA_HI(hn2, h3,  un23) }
    DOTC(0)  DOTC(1)  DOTC(2)  DOTC(3)
    DOTC(4)  DOTC(5)  DOTC(6)  DOTC(7)
    DOTC(8)  DOTC(9)  DOTC(10) DOTC(11)
    DOTC(12) DOTC(13) DOTC(14) DOTC(15)
#undef DOTC
#undef SV2
  }

  if (j == 0) {
    *(float2*)&out[NSAMP * NSTEP + s_base] = float2{logPa, logPb};
  }
}

extern "C" void kernel_launch(void* const* d_in, const int* in_sizes, int n_in,
                              void* d_out, int out_size, void* d_ws, size_t ws_size,
                              hipStream_t stream) {
  // inputs (setup_inputs order): nsamples(1), W(2x192), U(64x192), b(2x192),
  // Wd(64x2), bd(2) — float32
  const float* W  = (const float*)d_in[1];
  const float* U  = (const float*)d_in[2];
  const float* B  = (const float*)d_in[3];
  const float* Wd = (const float*)d_in[4];
  const float* Bd = (const float*)d_in[5];
  float* ws = (float*)d_ws;  // needs 48KB for packed U
  pack_kernel<<<dim3((HID * 192 + 255) / 256), dim3(256), 0, stream>>>(U, ws);
  vmc_kernel<<<dim3(NSAMP / CPB), dim3(HID), 0, stream>>>(
      W, ws, B, Wd, Bd, (float*)d_out);
}

// Round 9
// 344.634 us; speedup vs baseline: 4.2612x; 4.2612x over previous
//
#include <hip/hip_runtime.h>
#include <cstdint>
#include <math.h>

// GREEN since r6. Ladder: r15 490 -> r17 326 (pk_fma_f32 full-rate) -> r19
// 285 (DPP butterfly; 2-chain pk dot; U streamed via remat global loads).
// r20/r21/r22 PROVED: RA will never hold 192 U floats (caps ~136 VGPR).
// r23 (packed-ws, imm-offset global loads) = 1468us DISASTER: VGPR=32,
// VALUBusy 12.8% -> compiler issued the 48 loads as a SERIAL L2-latency
// chain; r19's addr-VALU was what hid that latency. Wall = max(issue,
// exposed latency).
// THIS ROUND r24: U lives in LDS, shared by 4 waves/block.
//  - 256-thr block = 4 waves x 2 chains (r19 per-wave structure verbatim),
//    grid 512 = exactly 2 blocks/CU all-resident, 2 waves/SIMD (= r19).
//  - U staged once/block to 48KB LDS float4 uq4[3][16][64] (lane-XOR
//    writer kills store-to-load forwarding; one barrier after staging).
//  - dot reads U as 48 ds_read_b128 with IMMEDIATE offsets off one base
//    (max 47KB < 64KB imm; 2-way bank aliasing = free). No barriers in
//    the step loop; waves decoupled; uq4/gsh read-only.
//  - diff vs r19: -192 global loads, -~350 addr VALU, +48 ds_read_b128
//    (LDS pipe, lgkmcnt-batched, ~120cyc latency covered by 2 waves/SIMD).
//  - LDS total 61.6KB <= 64KB static. Bit-identical arithmetic/PRNG ->
//    absmax must stay 0.0.
// Predict: dur 285 -> 150-210us, VALUBusy 55-70%, VGPR 100-140 (<=256
// keeps 2 blocks/CU), LDS ~61.6KB. Failure 250-300us = DS latency exposed
// -> revert r19.
// Locked-in: PRNG = partitionable threefry (key_t = tf((0,42),(0,t)); bits =
// o0^o1 of tf(key_t,(0,2s+cat))); f32 in/out; out = [4096*144][4096];
// decisions rounding-robust (6 arithmetic variants, bit-identical streams).

#define NSAMP 4096
#define NSTEP 144
#define HID 64
#define CPW 2              // chains per wave
#define WPB 4              // waves per block
#define CPBLK (CPW * WPB)  // 8 chains per block

typedef float v4f  __attribute__((ext_vector_type(4)));
typedef float v2f  __attribute__((ext_vector_type(2)));

// ---- JAX threefry2x32 (20 rounds, key-inject every 4) ----
__device__ __forceinline__ void threefry2x32(uint32_t k0, uint32_t k1,
                                             uint32_t x0, uint32_t x1,
                                             uint32_t& o0, uint32_t& o1) {
  const uint32_t ks0 = k0, ks1 = k1, ks2 = k0 ^ k1 ^ 0x1BD11BDAu;
  x0 += ks0; x1 += ks1;
#define TF_ROUND(d) { x0 += x1; x1 = (x1 << (d)) | (x1 >> (32 - (d))); x1 ^= x0; }
  TF_ROUND(13) TF_ROUND(15) TF_ROUND(26) TF_ROUND(6)
  x0 += ks1; x1 += ks2 + 1u;
  TF_ROUND(17) TF_ROUND(29) TF_ROUND(16) TF_ROUND(24)
  x0 += ks2; x1 += ks0 + 2u;
  TF_ROUND(13) TF_ROUND(15) TF_ROUND(26) TF_ROUND(6)
  x0 += ks0; x1 += ks1 + 3u;
  TF_ROUND(17) TF_ROUND(29) TF_ROUND(16) TF_ROUND(24)
  x0 += ks1; x1 += ks2 + 4u;
  TF_ROUND(13) TF_ROUND(15) TF_ROUND(26) TF_ROUND(6)
  x0 += ks2; x1 += ks0 + 5u;
#undef TF_ROUND
  o0 = x0; o1 = x1;
}

__device__ __forceinline__ float fsig(float x) {        // 1/(1+e^-x), stable
  return __builtin_amdgcn_rcpf(1.0f + __expf(-x));
}
__device__ __forceinline__ float ftanh(float x) {       // 1 - 2/(e^2x+1)
  const float e = __expf(2.0f * x);
  return 1.0f - 2.0f * __builtin_amdgcn_rcpf(e + 1.0f);
}

// Packed f32 FMA, chains (a,b) in (lo,hi). u-pair even-aligned; LO
// broadcasts its low element to both halves, HI the high one.
#define PKFMA_LO(acc, h2, up) \
  asm("v_pk_fma_f32 %0, %1, %2, %0 op_sel_hi:[1,0,1]" \
      : "+v"(acc) : "v"(h2), "v"(up));
#define PKFMA_HI(acc, h2, up) \
  asm("v_pk_fma_f32 %0, %1, %2, %0 op_sel:[0,1,0] op_sel_hi:[1,1,1]" \
      : "+v"(acc) : "v"(h2), "v"(up));

// DPP butterfly level: v += lane-swapped(v); bitwise == __shfl_xor(v,m)
// given the uniformity at each level (proven r19).
template <int CTRL>
__device__ __forceinline__ float dpp_add(float v) {
  union { float f; int i; } c; c.f = v;
  union { int i; float f; } r;
  r.i = __builtin_amdgcn_mov_dpp(c.i, CTRL, 0xF, 0xF, true);
  return v + r.f;
}
#define DPP_XOR1 0xB1
#define DPP_XOR2 0x4E
#define DPP_XOR4 0x141
#define DPP_XOR8 0x140

__global__ __launch_bounds__(256, 1) void vmc_kernel(
    const float* __restrict__ W, const float* __restrict__ U,
    const float* __restrict__ B, const float* __restrict__ Wd,
    const float* __restrict__ Bd, float* __restrict__ out) {
  const int tid = threadIdx.x;
  const int j = tid & 63;              // hidden unit owned by this lane
  const int w = tid >> 6;              // wave id in block
  const int s_blk = blockIdx.x * CPBLK;
  const int s_base = s_blk + w * CPW;  // first of this wave's 2 chains

  __shared__ __align__(16) float4 uq4[3 * 16 * 64];   // 48KB U pre-packed
  __shared__ __align__(16) float2 hsh2[WPB * HID];    // 2KB per-wave h
  __shared__ uint2 kkeys[NSTEP];                      // 1.15KB
  __shared__ float gsh[CPBLK * 2 * NSTEP];            // 9KB gumbels (all t)

  // --- phase 0: per-step keys: key_t = threefry((0,42),(0,t)) ---
  for (int t = tid; t < NSTEP; t += 256) {
    uint32_t o0, o1;
    threefry2x32(0u, 42u, 0u, (uint32_t)t, o0, o1);
    kkeys[t].x = o0; kkeys[t].y = o1;
  }
  __syncthreads();

  // --- phase 1a: U -> uq4 with lane-XOR writer (slot for lane l written by
  // lane l^1 -> cross-thread, store-to-load forwarding impossible).
  // slot v = g*1024 + q*64 + l holds {U[4q+e][g*64+l]}, e=0..3. ---
  for (int vv = tid; vv < 3 * 16 * 64; vv += 256) {
    const int v = (vv & ~63) | ((vv ^ 1) & 63);
    const int g = v >> 10, rem = v & 1023, q = rem >> 6;
    const int col = (g << 6) | (rem & 63);
    float4 x;
    x.x = U[(4 * q + 0) * 192 + col];
    x.y = U[(4 * q + 1) * 192 + col];
    x.z = U[(4 * q + 2) * 192 + col];
    x.w = U[(4 * q + 3) * 192 + col];
    uq4[v] = x;
  }

  // --- phase 1b: gumbels, EXACT path (f64 libm, one-time), all 144 steps
  // for the block's 8 chains: gsh[c8*288 + 2t + cat] ---
  for (int id = tid; id < CPBLK * 2 * NSTEP; id += 256) {
    const int c8 = id / 288;
    const int idx = id - c8 * 288;
    const uint2 kt = kkeys[idx >> 1];
    const uint32_t i = 2u * (uint32_t)(s_blk + c8) + (uint32_t)(idx & 1);
    uint32_t o0, o1;
    threefry2x32(kt.x, kt.y, 0u, i, o0, o1);
    const uint32_t bits = o0 ^ o1;
    union { uint32_t u; float f; } cv; cv.u = (bits >> 9) | 0x3F800000u;
    float uf = cv.f - 1.0f;
    uf = fmaxf(uf, 1.17549435e-38f);
    const float inner = (float)log((double)uf);
    gsh[id] = -(float)log((double)(-inner));
  }
  {
    float2* hw2i = &hsh2[w * HID];
    hw2i[j] = float2{0.0f, 0.0f};
  }
  __syncthreads();
  // After this barrier uq4/gsh are READ-ONLY; waves run decoupled (no
  // further barriers; each wave's hsh2 region is private, LDS ops are
  // program-ordered within a wave).

  float2* hw2 = &hsh2[w * HID];
  const float* gw = &gsh[(w * CPW) * (2 * NSTEP)];

  const float b1z = B[192 + j], b1r = B[256 + j], b1n = B[320 + j];
  const float b0z = B[j],       b0r = B[64 + j],  b0n = B[128 + j];
  const float xW0z = W[j]       + b0z, xW1z = W[192 + j] + b0z;
  const float xW0r = W[64 + j]  + b0r, xW1r = W[256 + j] + b0r;
  const float xW0n = W[128 + j] + b0n, xW1n = W[320 + j] + b0n;
  const float wdd = Wd[2*j + 1] - Wd[2*j];   // dense difference column
  const float bdd = Bd[1] - Bd[0];

  float ha = 0.0f, hb_ = 0.0f;
  float logPa = 0.0f, logPb = 0.0f;
  float axz = b0z, axr = b0r, axn = b0n;  // t=0: x=0 -> xm = b[0]
  float bxz = b0z, bxr = b0r, bxn = b0n;
  // loop-carried packed dot accumulators {chain a, chain b}; h_{-1}=0 -> 0
  v2f hz2 = {0.f, 0.f}, hr2 = {0.f, 0.f}, hn2 = {0.f, 0.f};

  for (int t = 0; t < NSTEP; ++t) {
    // ---- gates from the PREVIOUS iteration's dot (software pipeline) ----
    {
      const float az = axz + (hz2.x + b1z), ar = axr + (hr2.x + b1r);
      const float zz = fsig(az), rr = fsig(ar);
      const float hh = ftanh(axn + rr * (hn2.x + b1n));
      ha = zz * ha + (1.0f - zz) * hh;
    }
    {
      const float az = bxz + (hz2.y + b1z), ar = bxr + (hr2.y + b1r);
      const float zz = fsig(az), rr = fsig(ar);
      const float hh = ftanh(bxn + rr * (hn2.y + b1n));
      hb_ = zz * hb_ + (1.0f - zz) * hh;
    }
    hw2[j] = float2{ha, hb_};   // per-wave region: LDS ops in program order

    // ---- dense: difference-reduction, butterfly m=1..32. Levels 1-8 via
    // DPP VALU (bit-exact), 16/32 via shfl. ----
    float da = ha * wdd, db = hb_ * wdd;
    da = dpp_add<DPP_XOR1>(da); db = dpp_add<DPP_XOR1>(db);
    da = dpp_add<DPP_XOR2>(da); db = dpp_add<DPP_XOR2>(db);
    da = dpp_add<DPP_XOR4>(da); db = dpp_add<DPP_XOR4>(db);
    da = dpp_add<DPP_XOR8>(da); db = dpp_add<DPP_XOR8>(db);
    da += __shfl_xor(da, 16, 64); db += __shfl_xor(db, 16, 64);
    da += __shfl_xor(da, 32, 64); db += __shfl_xor(db, 32, 64);

    int sma, smb;
    {
      const float d = da + bdd;
      const float p1 = fsig(d), p0 = fsig(-d);
      const float lp0 = __logf(1e-10f + p0);
      const float lp1 = __logf(1e-10f + p1);
      const float g0 = gw[2*t], g1 = gw[2*t + 1];
      sma = (lp1 + g1) > (lp0 + g0);
      logPa += sma ? lp1 : lp0;
      axz = sma ? xW1z : xW0z;
      axr = sma ? xW1r : xW0r;
      axn = sma ? xW1n : xW0n;
    }
    {
      const float d = db + bdd;
      const float p1 = fsig(d), p0 = fsig(-d);
      const float lp0 = __logf(1e-10f + p0);
      const float lp1 = __logf(1e-10f + p1);
      const float g0 = gw[288 + 2*t], g1 = gw[288 + 2*t + 1];
      smb = (lp1 + g1) > (lp0 + g0);
      logPb += smb ? lp1 : lp0;
      bxz = smb ? xW1z : xW0z;
      bxr = smb ? xW1r : xW0r;
      bxn = smb ? xW1n : xW0n;
    }
    if (j == 0) {
      out[(s_base + 0) * NSTEP + t] = sma ? 1.0f : 0.0f;
      out[(s_base + 1) * NSTEP + t] = smb ? 1.0f : 0.0f;
    }

    // ---- dot for NEXT step: hm = h_t @ U, k-ascending per half, packed
    // {a,b}. h pairs from per-wave LDS broadcast; U from shared LDS uq4 via
    // ds_read_b128 with immediate offsets (base = &uq4[j], offs (g*16+q)KB).
    // Same values, same per-half order as r19 -> bit-identical decisions. ----
    hz2 = v2f{0.f, 0.f}; hr2 = v2f{0.f, 0.f}; hn2 = v2f{0.f, 0.f};
#define SV2(x, a, b) __builtin_shufflevector(x, x, a, b)
#define DOTC(c_) \
    { const v4f hA = *(const v4f*)&hw2[(c_)*4]; \
      const v4f hB = *(const v4f*)&hw2[(c_)*4 + 2]; \
      const v4f q0 = *(const v4f*)&uq4[          (c_)*64 + j]; \
      const v4f q1 = *(const v4f*)&uq4[1024 +    (c_)*64 + j]; \
      const v4f q2 = *(const v4f*)&uq4[2048 +    (c_)*64 + j]; \
      const v2f h0  = SV2(hA, 0, 1); \
      const v2f h1  = SV2(hA, 2, 3); \
      const v2f h2_ = SV2(hB, 0, 1); \
      const v2f h3  = SV2(hB, 2, 3); \
      const v2f uz01 = SV2(q0, 0, 1), uz23 = SV2(q0, 2, 3); \
      const v2f ur01 = SV2(q1, 0, 1), ur23 = SV2(q1, 2, 3); \
      const v2f un01 = SV2(q2, 0, 1), un23 = SV2(q2, 2, 3); \
      PKFMA_LO(hz2, h0,  uz01) PKFMA_LO(hr2, h0,  ur01) PKFMA_LO(hn2, h0,  un01) \
      PKFMA_HI(hz2, h1,  uz01) PKFMA_HI(hr2, h1,  ur01) PKFMA_HI(hn2, h1,  un01) \
      PKFMA_LO(hz2, h2_, uz23) PKFMA_LO(hr2, h2_, ur23) PKFMA_LO(hn2, h2_, un23) \
      PKFMA_HI(hz2, h3,  uz23) PKFMA_HI(hr2, h3,  ur23) PKFMA_HI(hn2, h3,  un23) }
    DOTC(0)  DOTC(1)  DOTC(2)  DOTC(3)
    DOTC(4)  DOTC(5)  DOTC(6)  DOTC(7)
    DOTC(8)  DOTC(9)  DOTC(10) DOTC(11)
    DOTC(12) DOTC(13) DOTC(14) DOTC(15)
#undef DOTC
#undef SV2
  }

  if (j == 0) {
    *(float2*)&out[NSAMP * NSTEP + s_base] = float2{logPa, logPb};
  }
}

extern "C" void kernel_launch(void* const* d_in, const int* in_sizes, int n_in,
                              void* d_out, int out_size, void* d_ws, size_t ws_size,
                              hipStream_t stream) {
  // inputs (setup_inputs order): nsamples(1), W(2x192), U(64x192), b(2x192),
  // Wd(64x2), bd(2) — float32
  const float* W  = (const float*)d_in[1];
  const float* U  = (const float*)d_in[2];
  const float* B  = (const float*)d_in[3];
  const float* Wd = (const float*)d_in[4];
  const float* Bd = (const float*)d_in[5];
  vmc_kernel<<<dim3(NSAMP / CPBLK), dim3(WPB * HID), 0, stream>>>(
      W, U, B, Wd, Bd, (float*)d_out);
}